// Round 2
// baseline (24180.878 us; speedup 1.0000x reference)
//
#include <hip/hip_runtime.h>
#include <cstdint>
#include <cstddef>

// MultiLayerLSTM on gfx950 — round 2: same structure as round 1 (infra flake),
// workspace trimmed via buffer aliasing (~260 MB).
// L=4 layers, B=64, T=256, D=H=1024.
// Per layer: big GEMM gx = in_seq @ Wih^T + b (parallel over T),
// then 256 sequential step kernels (recurrent matmul + fused LSTM cell).
// Final GEMM: logits = h_seq(layer3) @ Wout^T + b_out (f32 out).

#define LL 4
#define BB 64
#define TT 256
#define DD 1024
#define HH 1024
#define FOURH 4096

typedef __bf16 bf16;
typedef __bf16 bf16x8 __attribute__((ext_vector_type(8)));
typedef __bf16 bf16x4 __attribute__((ext_vector_type(4)));
typedef float f32x4 __attribute__((ext_vector_type(4)));

__device__ __forceinline__ void async_load16(const void* g, void* l) {
    __builtin_amdgcn_global_load_lds(
        (const __attribute__((address_space(1))) unsigned int*)g,
        (__attribute__((address_space(3))) unsigned int*)l,
        16, 0, 0);
}

__device__ __forceinline__ f32x4 mfma_bf16(bf16x8 a, bf16x8 b, f32x4 c) {
    return __builtin_amdgcn_mfma_f32_16x16x32_bf16(a, b, c, 0, 0, 0);
}

__device__ __forceinline__ float fsig(float x) {
    return 1.f / (1.f + __expf(-x));
}
__device__ __forceinline__ float ftanh(float x) {
    x = fminf(10.f, fmaxf(-10.f, x));
    float e = __expf(2.f * x);
    return (e - 1.f) / (e + 1.f);
}

// ---------------- f32 -> bf16 convert (vectorized x4) ----------------
__global__ void cvt_f32_bf16(const float* __restrict__ in, bf16* __restrict__ out, int n4) {
    int i = blockIdx.x * blockDim.x + threadIdx.x;
    if (i < n4) {
        float4 v = ((const float4*)in)[i];
        bf16x4 o = { (bf16)v.x, (bf16)v.y, (bf16)v.z, (bf16)v.w };
        ((bf16x4*)out)[i] = o;
    }
}

// ---------------- GEMM: C[M,N] = A[M,K] @ W[N,K]^T + bias[N] ----------------
// m97-style: 128x128 tile, BK=32, 256 threads (4 waves, each 64x64 subtile),
// global_load_lds staging, mfma_f32_16x16x32_bf16.
template <bool OUT_BF16>
__global__ __launch_bounds__(256) void gemm_bt(
    const bf16* __restrict__ A, const bf16* __restrict__ W,
    const float* __restrict__ bias, void* __restrict__ Cout,
    int M, int N, int K)
{
    __shared__ bf16 As[128 * 32];
    __shared__ bf16 Bs[128 * 32];
    const int tid = threadIdx.x;
    const int wave = tid >> 6, lane = tid & 63;
    const int lmod = lane & 15, lhalf = lane >> 4;
    const int m0 = blockIdx.y * 128, n0 = blockIdx.x * 128;
    const int wr = (wave >> 1) * 64, wc = (wave & 1) * 64;

    f32x4 acc[4][4] = {};

    const int arow = tid >> 2;        // 0..63
    const int acol = (tid & 3) * 8;   // 0,8,16,24
    const bf16* Ab  = A + (size_t)(m0 + arow) * K + acol;
    const bf16* Ab2 = A + (size_t)(m0 + 64 + arow) * K + acol;
    const bf16* Wb  = W + (size_t)(n0 + arow) * K + acol;
    const bf16* Wb2 = W + (size_t)(n0 + 64 + arow) * K + acol;

    for (int kc = 0; kc < K; kc += 32) {
        async_load16(Ab + kc,  &As[tid * 8]);
        async_load16(Ab2 + kc, &As[2048 + tid * 8]);
        async_load16(Wb + kc,  &Bs[tid * 8]);
        async_load16(Wb2 + kc, &Bs[2048 + tid * 8]);
        __syncthreads();  // compiler emits vmcnt(0) drain before barrier

        bf16x8 af[4], bfr[4];
#pragma unroll
        for (int mt = 0; mt < 4; mt++)
            af[mt] = *(const bf16x8*)&As[(wr + mt * 16 + lmod) * 32 + lhalf * 8];
#pragma unroll
        for (int nt = 0; nt < 4; nt++)
            bfr[nt] = *(const bf16x8*)&Bs[(wc + nt * 16 + lmod) * 32 + lhalf * 8];
#pragma unroll
        for (int mt = 0; mt < 4; mt++)
#pragma unroll
            for (int nt = 0; nt < 4; nt++)
                acc[mt][nt] = mfma_bf16(af[mt], bfr[nt], acc[mt][nt]);
        __syncthreads();
    }

#pragma unroll
    for (int mt = 0; mt < 4; mt++) {
#pragma unroll
        for (int nt = 0; nt < 4; nt++) {
            int n = n0 + wc + nt * 16 + lmod;
            float bv = bias[n];
#pragma unroll
            for (int r = 0; r < 4; r++) {
                int m = m0 + wr + mt * 16 + lhalf * 4 + r;
                float v = acc[mt][nt][r] + bv;
                if (OUT_BF16)
                    ((bf16*)Cout)[(size_t)m * N + n] = (bf16)v;
                else
                    ((float*)Cout)[(size_t)m * N + n] = v;
            }
        }
    }
}

// ---------------- LSTM step: G = gx_t + h_{t-1} @ Whh^T, then cell ----------------
// Grid: 64 blocks (16 hidden units each), 256 threads (wave w -> gate w).
// A (h_{t-1}) is [64 x 1024] with row stride Astride; staged per-BK-chunk in LDS.
__global__ __launch_bounds__(256) void lstm_step(
    const bf16* __restrict__ Abase, int Astride,
    const bf16* __restrict__ Whh,     // [4096 x 1024]
    const bf16* __restrict__ gx,      // [B*T x 4096], row = b*T + t
    float* __restrict__ ccur,         // [64 x 1024]
    bf16* __restrict__ hseq,          // [B*T x 1024], row = b*T + t
    float* __restrict__ outH, float* __restrict__ outC,  // only non-null at t = T-1
    int t)
{
    __shared__ bf16 As[64 * 32];     // one K-chunk of A
    __shared__ float Gs[4 * 64 * 16]; // gates i,f,g,o for 64 batch x 16 units

    const int tid = threadIdx.x;
    const int wave = tid >> 6, lane = tid & 63;
    const int lmod = lane & 15, lhalf = lane >> 4;
    const int j0 = blockIdx.x * 16;

    f32x4 acc[4] = {};

    const int arow = tid >> 2;
    const int acol = (tid & 3) * 8;
    const bf16* Ab = Abase + (size_t)arow * Astride + acol;
    const bf16* Wrow = Whh + (size_t)(wave * 1024 + j0 + lmod) * 1024 + lhalf * 8;

    for (int kc = 0; kc < 1024; kc += 32) {
        async_load16(Ab + kc, &As[tid * 8]);
        __syncthreads();
        bf16x8 bfrag = *(const bf16x8*)(Wrow + kc);
#pragma unroll
        for (int mt = 0; mt < 4; mt++) {
            bf16x8 afrag = *(const bf16x8*)&As[(mt * 16 + lmod) * 32 + lhalf * 8];
            acc[mt] = mfma_bf16(afrag, bfrag, acc[mt]);
        }
        __syncthreads();
    }

    // add gx, park gates in LDS for the cross-gate cell update
#pragma unroll
    for (int mt = 0; mt < 4; mt++) {
#pragma unroll
        for (int r = 0; r < 4; r++) {
            int m = mt * 16 + lhalf * 4 + r;  // batch row
            float g = acc[mt][r] +
                      (float)gx[(size_t)(m * TT + t) * FOURH + wave * 1024 + j0 + lmod];
            Gs[(wave * 64 + m) * 16 + lmod] = g;
        }
    }
    __syncthreads();

    // cell update: 64*16 = 1024 (batch, unit) pairs, 4 per thread, coalesced
#pragma unroll
    for (int q = 0; q < 4; q++) {
        int p = q * 256 + tid;
        int m = p >> 4;
        int jj = p & 15;
        float gi = Gs[(0 * 64 + m) * 16 + jj];
        float gf = Gs[(1 * 64 + m) * 16 + jj];
        float gg = Gs[(2 * 64 + m) * 16 + jj];
        float go = Gs[(3 * 64 + m) * 16 + jj];
        float* cp = ccur + m * 1024 + j0 + jj;
        float c = *cp;
        c = fsig(gf) * c + fsig(gi) * ftanh(gg);
        float h = fsig(go) * ftanh(c);
        *cp = c;
        hseq[(size_t)(m * TT + t) * HH + j0 + jj] = (bf16)h;
        if (outH) {
            outH[m * 1024 + j0 + jj] = h;
            outC[m * 1024 + j0 + jj] = c;
        }
    }
}

extern "C" void kernel_launch(void* const* d_in, const int* in_sizes, int n_in,
                              void* d_out, int out_size, void* d_ws, size_t ws_size,
                              hipStream_t stream) {
    const float* x    = (const float*)d_in[0];
    const float* h0   = (const float*)d_in[1];
    const float* c0   = (const float*)d_in[2];
    const float* Wih  = (const float*)d_in[3];
    const float* Whh  = (const float*)d_in[4];
    const float* bias = (const float*)d_in[5];
    const float* Wout = (const float*)d_in[6];
    const float* bout = (const float*)d_in[7];

    // ---- workspace layout (~260 MB) ----
    // x_bf doubles as one of the two hseq ping-pong buffers: x is only read by
    // layer 0's gx GEMM, after which the region is dead and layer 1+ can
    // overwrite it with hidden sequences.
    char* p = (char*)d_ws;
    bf16* x_bf    = (bf16*)p; p += (size_t)BB * TT * DD * 2;        // 32 MB (also hseqB)
    bf16* hseqA   = (bf16*)p; p += (size_t)BB * TT * HH * 2;        // 32 MB
    bf16* wih_bf  = (bf16*)p; p += (size_t)LL * FOURH * HH * 2;     // 32 MB
    bf16* whh_bf  = (bf16*)p; p += (size_t)LL * FOURH * HH * 2;     // 32 MB
    bf16* wout_bf = (bf16*)p; p += (size_t)DD * HH * 2;             // 2 MB
    bf16* h0_bf   = (bf16*)p; p += (size_t)LL * BB * HH * 2;        // 0.5 MB
    bf16* gx      = (bf16*)p; p += (size_t)BB * TT * FOURH * 2;     // 128 MB
    float* ccur   = (float*)p; p += (size_t)LL * BB * HH * 4;       // 1 MB
    if ((size_t)(p - (char*)d_ws) > ws_size) return;

    // ---- convert inputs to bf16 ----
    {
        struct { const float* in; bf16* out; size_t n; } jobs[5] = {
            { x,    x_bf,    (size_t)BB * TT * DD },
            { Wih,  wih_bf,  (size_t)LL * FOURH * HH },
            { Whh,  whh_bf,  (size_t)LL * FOURH * HH },
            { Wout, wout_bf, (size_t)DD * HH },
            { h0,   h0_bf,   (size_t)LL * BB * HH },
        };
        for (int j = 0; j < 5; j++) {
            int n4 = (int)(jobs[j].n / 4);
            cvt_f32_bf16<<<(n4 + 255) / 256, 256, 0, stream>>>(jobs[j].in, jobs[j].out, n4);
        }
    }
    hipMemcpyAsync(ccur, c0, (size_t)LL * BB * HH * 4, hipMemcpyDeviceToDevice, stream);

    float* logits = (float*)d_out;
    float* outH = logits + (size_t)BB * TT * DD;
    float* outC = outH + (size_t)LL * BB * HH;

    const bf16* inseq = x_bf;
    bf16* outseq = hseqA;
    for (int l = 0; l < LL; l++) {
        // gx = inseq @ Wih[l]^T + b[l]   (safe: reads inseq fully before steps
        // overwrite outseq, which is a different buffer)
        dim3 g1(FOURH / 128, (BB * TT) / 128);
        gemm_bt<true><<<g1, 256, 0, stream>>>(
            inseq, wih_bf + (size_t)l * FOURH * HH, bias + (size_t)l * FOURH,
            gx, BB * TT, FOURH, HH);

        for (int t = 0; t < TT; t++) {
            const bf16* Ab;
            int Astr;
            if (t == 0) { Ab = h0_bf + (size_t)l * BB * HH; Astr = HH; }
            else        { Ab = outseq + (size_t)(t - 1) * HH; Astr = TT * HH; }
            bool last = (t == TT - 1);
            lstm_step<<<64, 256, 0, stream>>>(
                Ab, Astr,
                whh_bf + (size_t)l * FOURH * HH, gx,
                ccur + (size_t)l * BB * HH, outseq,
                last ? (outH + (size_t)l * BB * HH) : nullptr,
                last ? (outC + (size_t)l * BB * HH) : nullptr,
                t);
        }
        // ping-pong: next layer reads what we just wrote; the buffer the next
        // layer writes (the old inseq region) is dead after the gx GEMM above.
        const bf16* new_in = outseq;
        outseq = (bf16*)inseq;  // reuse (x_bf on even layers)
        inseq = new_in;
    }

    // logits = h_seq(layer3) @ Wout^T + b_out  (f32 out)
    dim3 g2(DD / 128, (BB * TT) / 128);
    gemm_bt<false><<<g2, 256, 0, stream>>>(inseq, wout_bf, bout, logits, BB * TT, DD, HH);
}

// Round 3
// 22329.942 us; speedup vs baseline: 1.0829x; 1.0829x over previous
//
#include <hip/hip_runtime.h>
#include <cstdint>
#include <cstddef>

// MultiLayerLSTM on gfx950 — round 3: persistent per-layer recurrence kernel.
// L=4 layers, B=64, T=256, D=H=1024.
// Per layer: big GEMM gx = in_seq @ Wih^T + b (parallel over T), then ONE
// persistent kernel (64 blocks, 1/CU) runs all 256 timesteps with a hand-rolled
// device-scope grid barrier per step. Whh slice in VGPRs, cell state in regs,
// h_{t-1} staged wholesale into padded LDS each step.
// Final GEMM: logits = h_seq(layer3) @ Wout^T + b_out (f32 out).

#define LL 4
#define BB 64
#define TT 256
#define DD 1024
#define HH 1024
#define FOURH 4096
#define APAD 1032   // padded LDS row stride (bf16 elems): +8 kills bank conflicts

typedef __bf16 bf16;
typedef __bf16 bf16x8 __attribute__((ext_vector_type(8)));
typedef __bf16 bf16x4 __attribute__((ext_vector_type(4)));
typedef float f32x4 __attribute__((ext_vector_type(4)));

__device__ __forceinline__ void async_load16(const void* g, void* l) {
    __builtin_amdgcn_global_load_lds(
        (const __attribute__((address_space(1))) unsigned int*)g,
        (__attribute__((address_space(3))) unsigned int*)l,
        16, 0, 0);
}

__device__ __forceinline__ f32x4 mfma_bf16(bf16x8 a, bf16x8 b, f32x4 c) {
    return __builtin_amdgcn_mfma_f32_16x16x32_bf16(a, b, c, 0, 0, 0);
}

__device__ __forceinline__ float fsig(float x) {
    return 1.f / (1.f + __expf(-x));
}
__device__ __forceinline__ float ftanh(float x) {
    x = fminf(10.f, fmaxf(-10.f, x));
    float e = __expf(2.f * x);
    return (e - 1.f) / (e + 1.f);
}

// ---------------- f32 -> bf16 convert (vectorized x4) ----------------
__global__ void cvt_f32_bf16(const float* __restrict__ in, bf16* __restrict__ out, int n4) {
    int i = blockIdx.x * blockDim.x + threadIdx.x;
    if (i < n4) {
        float4 v = ((const float4*)in)[i];
        bf16x4 o = { (bf16)v.x, (bf16)v.y, (bf16)v.z, (bf16)v.w };
        ((bf16x4*)out)[i] = o;
    }
}

// ---------------- GEMM: C[M,N] = A[M,K] @ W[N,K]^T + bias[N] ----------------
template <bool OUT_BF16>
__global__ __launch_bounds__(256) void gemm_bt(
    const bf16* __restrict__ A, const bf16* __restrict__ W,
    const float* __restrict__ bias, void* __restrict__ Cout,
    int M, int N, int K)
{
    __shared__ bf16 As[128 * 32];
    __shared__ bf16 Bs[128 * 32];
    const int tid = threadIdx.x;
    const int wave = tid >> 6, lane = tid & 63;
    const int lmod = lane & 15, lhalf = lane >> 4;
    const int m0 = blockIdx.y * 128, n0 = blockIdx.x * 128;
    const int wr = (wave >> 1) * 64, wc = (wave & 1) * 64;

    f32x4 acc[4][4] = {};

    const int arow = tid >> 2;
    const int acol = (tid & 3) * 8;
    const bf16* Ab  = A + (size_t)(m0 + arow) * K + acol;
    const bf16* Ab2 = A + (size_t)(m0 + 64 + arow) * K + acol;
    const bf16* Wb  = W + (size_t)(n0 + arow) * K + acol;
    const bf16* Wb2 = W + (size_t)(n0 + 64 + arow) * K + acol;

    for (int kc = 0; kc < K; kc += 32) {
        async_load16(Ab + kc,  &As[tid * 8]);
        async_load16(Ab2 + kc, &As[2048 + tid * 8]);
        async_load16(Wb + kc,  &Bs[tid * 8]);
        async_load16(Wb2 + kc, &Bs[2048 + tid * 8]);
        __syncthreads();

        bf16x8 af[4], bfr[4];
#pragma unroll
        for (int mt = 0; mt < 4; mt++)
            af[mt] = *(const bf16x8*)&As[(wr + mt * 16 + lmod) * 32 + lhalf * 8];
#pragma unroll
        for (int nt = 0; nt < 4; nt++)
            bfr[nt] = *(const bf16x8*)&Bs[(wc + nt * 16 + lmod) * 32 + lhalf * 8];
#pragma unroll
        for (int mt = 0; mt < 4; mt++)
#pragma unroll
            for (int nt = 0; nt < 4; nt++)
                acc[mt][nt] = mfma_bf16(af[mt], bfr[nt], acc[mt][nt]);
        __syncthreads();
    }

#pragma unroll
    for (int mt = 0; mt < 4; mt++) {
#pragma unroll
        for (int nt = 0; nt < 4; nt++) {
            int n = n0 + wc + nt * 16 + lmod;
            float bv = bias[n];
#pragma unroll
            for (int r = 0; r < 4; r++) {
                int m = m0 + wr + mt * 16 + lhalf * 4 + r;
                float v = acc[mt][nt][r] + bv;
                if (OUT_BF16)
                    ((bf16*)Cout)[(size_t)m * N + n] = (bf16)v;
                else
                    ((float*)Cout)[(size_t)m * N + n] = v;
            }
        }
    }
}

// ---------------- Persistent LSTM layer kernel ----------------
// 64 blocks x 256 threads, 1 block/CU (149.5 KB LDS) -> all co-resident.
// Block owns 16 hidden units (j0..j0+15); wave w computes gate w.
// Whh slice (16 rows/wave) lives in VGPRs; cell state in regs; per step the
// full h_{t-1} [64x1024] is staged into padded LDS, then an unbarriered
// MFMA K-loop, gate exchange via LDS, fused cell update, grid barrier.
__global__ __launch_bounds__(256, 1) void lstm_layer(
    const bf16* __restrict__ h0,     // [64*1024] this layer's initial h
    const float* __restrict__ c0,    // [64*1024] this layer's initial c (f32 input)
    const bf16* __restrict__ Whh,    // [4096*1024] this layer's recurrent weights
    const bf16* __restrict__ gx,     // [B*T, 4096], row = b*T + t
    bf16* __restrict__ hseq,         // [B*T, 1024], row = b*T + t
    bf16* __restrict__ hbuf0, bf16* __restrict__ hbuf1,  // compact [64*1024] ping-pong
    float* __restrict__ outH, float* __restrict__ outC,  // [64*1024] finals
    int* __restrict__ ctr)           // zeroed barrier counter (monotonic)
{
    __shared__ bf16 As[64 * APAD];       // 132 KB padded h_{t-1}
    __shared__ float Gs[4 * 64 * 17];    // 17.4 KB gate exchange (padded)

    const int tid = threadIdx.x;
    const int wave = tid >> 6, lane = tid & 63;
    const int lmod = lane & 15, lhalf = lane >> 4;
    const int j0 = blockIdx.x * 16;

    // ---- load persistent Whh fragments: wave w = gate w, unit row j0+lmod ----
    bf16x8 wfrag[32];
    {
        const bf16* wrow = Whh + ((size_t)(wave * 1024 + j0 + lmod)) * 1024 + lhalf * 8;
#pragma unroll
        for (int kc = 0; kc < 32; kc++)
            wfrag[kc] = *(const bf16x8*)(wrow + kc * 32);
    }

    // ---- persistent cell state: thread owns (m,jj) pairs p = q*256 + tid ----
    float creg[4];
#pragma unroll
    for (int q = 0; q < 4; q++) {
        int p = q * 256 + tid;
        creg[q] = c0[(p >> 4) * 1024 + j0 + (p & 15)];
    }

    for (int t = 0; t < TT; t++) {
        const bf16* src = (t == 0) ? h0 : ((t & 1) ? hbuf0 : hbuf1);
        bf16* wbuf = (t & 1) ? hbuf1 : hbuf0;

        // stage h_{t-1} [64x1024] -> padded LDS (linear global reads, padded writes)
#pragma unroll
        for (int i = 0; i < 32; i++) {
            int e = i * 2048 + tid * 8;
            bf16x8 v = *(const bf16x8*)(src + e);
            *(bf16x8*)&As[(e >> 10) * APAD + (e & 1023)] = v;
        }
        __syncthreads();

        // recurrent matmul: 64 batches x 16 rows (this wave's gate), K=1024
        f32x4 acc[4] = {};
#pragma unroll
        for (int kc = 0; kc < 32; kc++) {
#pragma unroll
            for (int mt = 0; mt < 4; mt++) {
                bf16x8 a = *(const bf16x8*)&As[(mt * 16 + lmod) * APAD + kc * 32 + lhalf * 8];
                acc[mt] = mfma_bf16(a, wfrag[kc], acc[mt]);
            }
        }

        // add precomputed input projection, park gates in LDS
#pragma unroll
        for (int mt = 0; mt < 4; mt++) {
#pragma unroll
            for (int r = 0; r < 4; r++) {
                int m = mt * 16 + lhalf * 4 + r;  // batch row
                float g = acc[mt][r] +
                          (float)gx[((size_t)(m * TT + t)) * FOURH + wave * 1024 + j0 + lmod];
                Gs[(wave * 64 + m) * 17 + lmod] = g;
            }
        }
        __syncthreads();

        // fused cell update; c stays in regs, h published to ping-pong + hseq
        const bool lastt = (t == TT - 1);
#pragma unroll
        for (int q = 0; q < 4; q++) {
            int p = q * 256 + tid;
            int m = p >> 4, jj = p & 15;
            float gi = Gs[(0 * 64 + m) * 17 + jj];
            float gf = Gs[(1 * 64 + m) * 17 + jj];
            float gg = Gs[(2 * 64 + m) * 17 + jj];
            float go = Gs[(3 * 64 + m) * 17 + jj];
            float c = fsig(gf) * creg[q] + fsig(gi) * ftanh(gg);
            float h = fsig(go) * ftanh(c);
            creg[q] = c;
            bf16 hb = (bf16)h;
            wbuf[m * 1024 + j0 + jj] = hb;
            hseq[((size_t)(m * TT + t)) * HH + j0 + jj] = hb;
            if (lastt) {
                outH[m * 1024 + j0 + jj] = h;
                outC[m * 1024 + j0 + jj] = c;
            }
        }

        // grid barrier: device-scope release/acquire (cross-XCD visibility),
        // monotonic counter (no reset race). Also guards As/Gs reuse next step.
        __syncthreads();
        if (tid == 0) {
            __hip_atomic_fetch_add(ctr, 1, __ATOMIC_RELEASE, __HIP_MEMORY_SCOPE_AGENT);
            const int target = 64 * (t + 1);
            while (__hip_atomic_load(ctr, __ATOMIC_ACQUIRE, __HIP_MEMORY_SCOPE_AGENT) < target)
                __builtin_amdgcn_s_sleep(8);
        }
        __syncthreads();
    }
}

extern "C" void kernel_launch(void* const* d_in, const int* in_sizes, int n_in,
                              void* d_out, int out_size, void* d_ws, size_t ws_size,
                              hipStream_t stream) {
    const float* x    = (const float*)d_in[0];
    const float* h0   = (const float*)d_in[1];
    const float* c0   = (const float*)d_in[2];
    const float* Wih  = (const float*)d_in[3];
    const float* Whh  = (const float*)d_in[4];
    const float* bias = (const float*)d_in[5];
    const float* Wout = (const float*)d_in[6];
    const float* bout = (const float*)d_in[7];

    // ---- workspace layout (~260 MB) ----
    char* p = (char*)d_ws;
    int*  ctrs    = (int*)p;  p += 256;                              // barrier counters
    bf16* x_bf    = (bf16*)p; p += (size_t)BB * TT * DD * 2;         // 32 MB (hseq ping)
    bf16* hseqA   = (bf16*)p; p += (size_t)BB * TT * HH * 2;         // 32 MB (hseq pong)
    bf16* wih_bf  = (bf16*)p; p += (size_t)LL * FOURH * HH * 2;      // 32 MB
    bf16* whh_bf  = (bf16*)p; p += (size_t)LL * FOURH * HH * 2;      // 32 MB
    bf16* wout_bf = (bf16*)p; p += (size_t)DD * HH * 2;              // 2 MB
    bf16* h0_bf   = (bf16*)p; p += (size_t)LL * BB * HH * 2;         // 0.5 MB
    bf16* gx      = (bf16*)p; p += (size_t)BB * TT * FOURH * 2;      // 128 MB
    bf16* hbuf0   = (bf16*)p; p += (size_t)BB * HH * 2;              // 128 KB
    bf16* hbuf1   = (bf16*)p; p += (size_t)BB * HH * 2;              // 128 KB
    if ((size_t)(p - (char*)d_ws) > ws_size) return;

    hipMemsetAsync(ctrs, 0, 256, stream);

    // ---- convert inputs to bf16 ----
    {
        struct { const float* in; bf16* out; size_t n; } jobs[5] = {
            { x,    x_bf,    (size_t)BB * TT * DD },
            { Wih,  wih_bf,  (size_t)LL * FOURH * HH },
            { Whh,  whh_bf,  (size_t)LL * FOURH * HH },
            { Wout, wout_bf, (size_t)DD * HH },
            { h0,   h0_bf,   (size_t)LL * BB * HH },
        };
        for (int j = 0; j < 5; j++) {
            int n4 = (int)(jobs[j].n / 4);
            cvt_f32_bf16<<<(n4 + 255) / 256, 256, 0, stream>>>(jobs[j].in, jobs[j].out, n4);
        }
    }

    float* logits = (float*)d_out;
    float* outH = logits + (size_t)BB * TT * DD;
    float* outC = outH + (size_t)LL * BB * HH;

    const bf16* inseq = x_bf;
    bf16* outseq = hseqA;
    for (int l = 0; l < LL; l++) {
        dim3 g1(FOURH / 128, (BB * TT) / 128);
        gemm_bt<true><<<g1, 256, 0, stream>>>(
            inseq, wih_bf + (size_t)l * FOURH * HH, bias + (size_t)l * FOURH,
            gx, BB * TT, FOURH, HH);

        lstm_layer<<<64, 256, 0, stream>>>(
            h0_bf + (size_t)l * BB * HH, c0 + (size_t)l * BB * HH,
            whh_bf + (size_t)l * FOURH * HH, gx,
            outseq, hbuf0, hbuf1,
            outH + (size_t)l * BB * HH, outC + (size_t)l * BB * HH,
            ctrs + l);

        const bf16* new_in = outseq;
        outseq = (bf16*)inseq;   // old input buffer is dead after the gx GEMM
        inseq = new_in;
    }

    dim3 g2(DD / 128, (BB * TT) / 128);
    gemm_bt<false><<<g2, 256, 0, stream>>>(inseq, wout_bf, bout, logits, BB * TT, DD, HH);
}

// Round 4
// 17952.690 us; speedup vs baseline: 1.3469x; 1.2438x over previous
//
#include <hip/hip_runtime.h>
#include <cstdint>
#include <cstddef>

// MultiLayerLSTM on gfx950 — round 4: persistent per-layer kernel with
// flags-array grid barrier (no atomic RMW chain) and [T][B][feat] layout
// (contiguous per-step slabs; hseq doubles as the h ping-pong).
// L=4 layers, B=64, T=256, D=H=1024.

#define LL 4
#define BB 64
#define TT 256
#define DD 1024
#define HH 1024
#define FOURH 4096
#define APAD 1032   // padded LDS row stride (bf16 elems)

typedef __bf16 bf16;
typedef __bf16 bf16x8 __attribute__((ext_vector_type(8)));
typedef __bf16 bf16x4 __attribute__((ext_vector_type(4)));
typedef __bf16 bf16x2 __attribute__((ext_vector_type(2)));
typedef float f32x4 __attribute__((ext_vector_type(4)));

__device__ __forceinline__ void async_load16(const void* g, void* l) {
    __builtin_amdgcn_global_load_lds(
        (const __attribute__((address_space(1))) unsigned int*)g,
        (__attribute__((address_space(3))) unsigned int*)l,
        16, 0, 0);
}

__device__ __forceinline__ f32x4 mfma_bf16(bf16x8 a, bf16x8 b, f32x4 c) {
    return __builtin_amdgcn_mfma_f32_16x16x32_bf16(a, b, c, 0, 0, 0);
}

__device__ __forceinline__ float fsig(float x) {
    return 1.f / (1.f + __expf(-x));
}
__device__ __forceinline__ float ftanh(float x) {
    x = fminf(10.f, fmaxf(-10.f, x));
    float e = __expf(2.f * x);
    return (e - 1.f) / (e + 1.f);
}

// ---------------- f32 -> bf16 convert (vectorized x4) ----------------
__global__ void cvt_f32_bf16(const float* __restrict__ in, bf16* __restrict__ out, int n4) {
    int i = blockIdx.x * blockDim.x + threadIdx.x;
    if (i < n4) {
        float4 v = ((const float4*)in)[i];
        bf16x4 o = { (bf16)v.x, (bf16)v.y, (bf16)v.z, (bf16)v.w };
        ((bf16x4*)out)[i] = o;
    }
}

// x [B][T][D] f32 -> x_bf [T][B][D] bf16. One block per (b,t) row.
__global__ __launch_bounds__(256) void cvt_x_transpose(
    const float* __restrict__ x, bf16* __restrict__ out) {
    int bx = blockIdx.x;           // = b*TT + t
    int b = bx >> 8, t = bx & 255;
    int tid = threadIdx.x;
    float4 v = ((const float4*)(x + (size_t)bx * DD))[tid];
    bf16x4 o = { (bf16)v.x, (bf16)v.y, (bf16)v.z, (bf16)v.w };
    ((bf16x4*)(out + ((size_t)(t * BB + b)) * DD))[tid] = o;
}

// ---------------- GEMM: C[M,N] = A[M,K] @ W[N,K]^T + bias[N] ----------------
// REMAP: output row m = t*B+b is written to row b*TT+t (f32 logits in [B][T]).
template <bool OUT_BF16, bool REMAP>
__global__ __launch_bounds__(256) void gemm_bt(
    const bf16* __restrict__ A, const bf16* __restrict__ W,
    const float* __restrict__ bias, void* __restrict__ Cout,
    int M, int N, int K)
{
    __shared__ bf16 As[128 * 32];
    __shared__ bf16 Bs[128 * 32];
    const int tid = threadIdx.x;
    const int wave = tid >> 6, lane = tid & 63;
    const int lmod = lane & 15, lhalf = lane >> 4;
    const int m0 = blockIdx.y * 128, n0 = blockIdx.x * 128;
    const int wr = (wave >> 1) * 64, wc = (wave & 1) * 64;

    f32x4 acc[4][4] = {};

    const int arow = tid >> 2;
    const int acol = (tid & 3) * 8;
    const bf16* Ab  = A + (size_t)(m0 + arow) * K + acol;
    const bf16* Ab2 = A + (size_t)(m0 + 64 + arow) * K + acol;
    const bf16* Wb  = W + (size_t)(n0 + arow) * K + acol;
    const bf16* Wb2 = W + (size_t)(n0 + 64 + arow) * K + acol;

    for (int kc = 0; kc < K; kc += 32) {
        async_load16(Ab + kc,  &As[tid * 8]);
        async_load16(Ab2 + kc, &As[2048 + tid * 8]);
        async_load16(Wb + kc,  &Bs[tid * 8]);
        async_load16(Wb2 + kc, &Bs[2048 + tid * 8]);
        __syncthreads();

        bf16x8 af[4], bfr[4];
#pragma unroll
        for (int mt = 0; mt < 4; mt++)
            af[mt] = *(const bf16x8*)&As[(wr + mt * 16 + lmod) * 32 + lhalf * 8];
#pragma unroll
        for (int nt = 0; nt < 4; nt++)
            bfr[nt] = *(const bf16x8*)&Bs[(wc + nt * 16 + lmod) * 32 + lhalf * 8];
#pragma unroll
        for (int mt = 0; mt < 4; mt++)
#pragma unroll
            for (int nt = 0; nt < 4; nt++)
                acc[mt][nt] = mfma_bf16(af[mt], bfr[nt], acc[mt][nt]);
        __syncthreads();
    }

#pragma unroll
    for (int mt = 0; mt < 4; mt++) {
#pragma unroll
        for (int nt = 0; nt < 4; nt++) {
            int n = n0 + wc + nt * 16 + lmod;
            float bv = bias[n];
#pragma unroll
            for (int r = 0; r < 4; r++) {
                int m = m0 + wr + mt * 16 + lhalf * 4 + r;
                int orow = REMAP ? ((m & 63) * TT + (m >> 6)) : m;
                float v = acc[mt][nt][r] + bv;
                if (OUT_BF16)
                    ((bf16*)Cout)[(size_t)orow * N + n] = (bf16)v;
                else
                    ((float*)Cout)[(size_t)orow * N + n] = v;
            }
        }
    }
}

// ---------------- Persistent LSTM layer kernel ----------------
// 64 blocks x 256 threads, 1 block/CU. Block owns 16 hidden units; wave w =
// gate w. Whh slice in VGPRs; cell state in regs. Per step: gx prefetch
// (read-only, hoisted above the wait), flags-array grid barrier with explicit
// agent fences, h_{t-1} staged from hseq[t-1] slab into padded LDS, MFMA,
// gate exchange in LDS, fused cell update, publish h to hseq[t] slab.
__global__ __launch_bounds__(256, 1) void lstm_layer(
    const bf16* __restrict__ h0,     // [B*H] this layer's initial h (bf16)
    const float* __restrict__ c0,    // [B*H] this layer's initial c (f32)
    const bf16* __restrict__ Whh,    // [4H*H]
    const bf16* __restrict__ gx,     // [T*B, 4H], row = t*B + b
    bf16* __restrict__ hseq,         // [T*B, H],  row = t*B + b
    float* __restrict__ outH, float* __restrict__ outC,  // [B*H] finals
    int* __restrict__ flags)         // [64] zeroed per layer
{
    __shared__ bf16 As[64 * APAD];       // 132 KB padded h_{t-1}
    __shared__ float Gs[4 * 64 * 17];    // 17.4 KB gate exchange

    const int tid = threadIdx.x;
    const int wave = tid >> 6, lane = tid & 63;
    const int lmod = lane & 15, lhalf = lane >> 4;
    const int j0 = blockIdx.x * 16;
    const int bid = blockIdx.x;

    // persistent Whh fragments: wave w = gate w, unit row j0+lmod
    bf16x8 wfrag[32];
    {
        const bf16* wrow = Whh + ((size_t)(wave * 1024 + j0 + lmod)) * 1024 + lhalf * 8;
#pragma unroll
        for (int kc = 0; kc < 32; kc++)
            wfrag[kc] = *(const bf16x8*)(wrow + kc * 32);
    }

    // persistent cell state: thread owns (m, jj) and (m, jj+1) at p=q*512+tid*2
    float2 creg[2];
#pragma unroll
    for (int q = 0; q < 2; q++) {
        int p = q * 512 + tid * 2;
        creg[q] = *(const float2*)&c0[(p >> 4) * 1024 + j0 + (p & 15)];
    }

    for (int t = 0; t < TT; t++) {
        // gx prefetch: depends only on t, read-only -> safe before the barrier
        float gxr[4][4];
#pragma unroll
        for (int mt = 0; mt < 4; mt++)
#pragma unroll
            for (int r = 0; r < 4; r++) {
                int m = mt * 16 + lhalf * 4 + r;
                gxr[mt][r] =
                    (float)gx[((size_t)(t * BB + m)) * FOURH + wave * 1024 + j0 + lmod];
            }

        // flags-array grid barrier: wave 0, one lane per peer block, no RMW
        if (t > 0 && wave == 0) {
            for (;;) {
                int v = __hip_atomic_load(&flags[lane], __ATOMIC_RELAXED,
                                          __HIP_MEMORY_SCOPE_AGENT);
                if (__all(v >= t)) break;
            }
        }
        __syncthreads();
        if (t > 0) __builtin_amdgcn_fence(__ATOMIC_ACQUIRE, "agent");

        // stage h_{t-1} [64x1024] contiguous slab -> padded LDS
        const bf16* src = (t == 0) ? h0 : (hseq + (size_t)(t - 1) * BB * HH);
#pragma unroll
        for (int i = 0; i < 32; i++) {
            int e = i * 2048 + tid * 8;
            bf16x8 v = *(const bf16x8*)(src + e);
            *(bf16x8*)&As[(e >> 10) * APAD + (e & 1023)] = v;
        }
        __syncthreads();

        // recurrent matmul: 64 batches x 16 units (this wave's gate), K=1024
        f32x4 acc[4] = {};
#pragma unroll
        for (int kc = 0; kc < 32; kc++) {
#pragma unroll
            for (int mt = 0; mt < 4; mt++) {
                bf16x8 a = *(const bf16x8*)&As[(mt * 16 + lmod) * APAD + kc * 32 + lhalf * 8];
                acc[mt] = mfma_bf16(a, wfrag[kc], acc[mt]);
            }
        }

        // add input projection, park gates in LDS
#pragma unroll
        for (int mt = 0; mt < 4; mt++)
#pragma unroll
            for (int r = 0; r < 4; r++) {
                int m = mt * 16 + lhalf * 4 + r;
                Gs[(wave * 64 + m) * 17 + lmod] = acc[mt][r] + gxr[mt][r];
            }
        __syncthreads();

        // fused cell update; publish h to hseq[t] slab (packed bf16x2)
        const bool lastt = (t == TT - 1);
#pragma unroll
        for (int q = 0; q < 2; q++) {
            int p = q * 512 + tid * 2;
            int m = p >> 4, jj = p & 15;
            float cv[2], hv[2];
#pragma unroll
            for (int u = 0; u < 2; u++) {
                float gi = Gs[(0 * 64 + m) * 17 + jj + u];
                float gf = Gs[(1 * 64 + m) * 17 + jj + u];
                float gg = Gs[(2 * 64 + m) * 17 + jj + u];
                float go = Gs[(3 * 64 + m) * 17 + jj + u];
                float cprev = u ? creg[q].y : creg[q].x;
                float c = fsig(gf) * cprev + fsig(gi) * ftanh(gg);
                float h = fsig(go) * ftanh(c);
                cv[u] = c; hv[u] = h;
            }
            creg[q].x = cv[0]; creg[q].y = cv[1];
            bf16x2 hp = { (bf16)hv[0], (bf16)hv[1] };
            *(bf16x2*)&hseq[((size_t)(t * BB + m)) * HH + j0 + jj] = hp;
            if (lastt) {
                *(float2*)&outH[m * 1024 + j0 + jj] = make_float2(hv[0], hv[1]);
                *(float2*)&outC[m * 1024 + j0 + jj] = make_float2(cv[0], cv[1]);
            }
        }

        // publish: drain stores (syncthreads waits vmcnt), release, own flag
        __syncthreads();
        if (tid == 0) {
            __builtin_amdgcn_fence(__ATOMIC_RELEASE, "agent");
            __hip_atomic_store(&flags[bid], t + 1, __ATOMIC_RELAXED,
                               __HIP_MEMORY_SCOPE_AGENT);
        }
    }
}

extern "C" void kernel_launch(void* const* d_in, const int* in_sizes, int n_in,
                              void* d_out, int out_size, void* d_ws, size_t ws_size,
                              hipStream_t stream) {
    const float* x    = (const float*)d_in[0];
    const float* h0   = (const float*)d_in[1];
    const float* c0   = (const float*)d_in[2];
    const float* Wih  = (const float*)d_in[3];
    const float* Whh  = (const float*)d_in[4];
    const float* bias = (const float*)d_in[5];
    const float* Wout = (const float*)d_in[6];
    const float* bout = (const float*)d_in[7];

    // ---- workspace layout (~260 MB) ----
    char* p = (char*)d_ws;
    int*  ctrs    = (int*)p;  p += 1024;                             // 4 x 64 flags
    bf16* x_bf    = (bf16*)p; p += (size_t)BB * TT * DD * 2;         // 32 MB ([T][B][D])
    bf16* hseqA   = (bf16*)p; p += (size_t)BB * TT * HH * 2;         // 32 MB
    bf16* wih_bf  = (bf16*)p; p += (size_t)LL * FOURH * HH * 2;      // 32 MB
    bf16* whh_bf  = (bf16*)p; p += (size_t)LL * FOURH * HH * 2;      // 32 MB
    bf16* wout_bf = (bf16*)p; p += (size_t)DD * HH * 2;              // 2 MB
    bf16* h0_bf   = (bf16*)p; p += (size_t)LL * BB * HH * 2;         // 0.5 MB
    bf16* gx      = (bf16*)p; p += (size_t)BB * TT * FOURH * 2;      // 128 MB
    if ((size_t)(p - (char*)d_ws) > ws_size) return;

    hipMemsetAsync(ctrs, 0, 1024, stream);

    // ---- convert inputs to bf16 ----
    cvt_x_transpose<<<BB * TT, 256, 0, stream>>>(x, x_bf);
    {
        struct { const float* in; bf16* out; size_t n; } jobs[4] = {
            { Wih,  wih_bf,  (size_t)LL * FOURH * HH },
            { Whh,  whh_bf,  (size_t)LL * FOURH * HH },
            { Wout, wout_bf, (size_t)DD * HH },
            { h0,   h0_bf,   (size_t)LL * BB * HH },
        };
        for (int j = 0; j < 4; j++) {
            int n4 = (int)(jobs[j].n / 4);
            cvt_f32_bf16<<<(n4 + 255) / 256, 256, 0, stream>>>(jobs[j].in, jobs[j].out, n4);
        }
    }

    float* logits = (float*)d_out;
    float* outH = logits + (size_t)BB * TT * DD;
    float* outC = outH + (size_t)LL * BB * HH;

    const bf16* inseq = x_bf;
    bf16* outseq = hseqA;
    for (int l = 0; l < LL; l++) {
        dim3 g1(FOURH / 128, (BB * TT) / 128);
        gemm_bt<true, false><<<g1, 256, 0, stream>>>(
            inseq, wih_bf + (size_t)l * FOURH * HH, bias + (size_t)l * FOURH,
            gx, BB * TT, FOURH, HH);

        lstm_layer<<<64, 256, 0, stream>>>(
            h0_bf + (size_t)l * BB * HH, c0 + (size_t)l * BB * HH,
            whh_bf + (size_t)l * FOURH * HH, gx,
            outseq,
            outH + (size_t)l * BB * HH, outC + (size_t)l * BB * HH,
            ctrs + l * 64);

        const bf16* new_in = outseq;
        outseq = (bf16*)inseq;   // old input slab is dead after the gx GEMM
        inseq = new_in;
    }

    dim3 g2(DD / 128, (BB * TT) / 128);
    gemm_bt<false, true><<<g2, 256, 0, stream>>>(
        inseq, wout_bf, bout, logits, BB * TT, DD, HH);
}